// Round 12
// baseline (194.746 us; speedup 1.0000x reference)
//
#include <hip/hip_runtime.h>

#define N_TOK 256
#define CP    128
#define CHD   32
#define NH    4
#define NT    65536   // N_TOK*N_TOK
#define NCOL  528     // 512 (q|k|v|g) + 4 (b) + 12 pad
#define VTP   268     // LDS pitch (shorts)
#define LOG2E 1.4426950408889634f

typedef short short8 __attribute__((ext_vector_type(8)));
typedef float f32x4  __attribute__((ext_vector_type(4)));
typedef float f32x2  __attribute__((ext_vector_type(2)));

__device__ __forceinline__ short f2bf(float f) {
    unsigned u = __builtin_bit_cast(unsigned, f);
    u += 0x7fffu + ((u >> 16) & 1u);   // RTNE
    return (short)(u >> 16);
}
__device__ __forceinline__ float bf2f(short s) {
    unsigned u = ((unsigned)(unsigned short)s) << 16;
    return __builtin_bit_cast(float, u);
}
// pack two f32 -> one dword of 2x bf16 (lo=a, hi=b) in ONE instruction.
// Only used where the packed dword is STORED WHOLE (R11 lesson: pack-then-
// split into b16 stores is a regression).
__device__ __forceinline__ unsigned cvtpk(float a, float b) {
    unsigned r;
    asm("v_cvt_pk_bf16_f32 %0, %1, %2" : "=v"(r) : "v"(a), "v"(b));
    return r;
}
// native 2^x
__device__ __forceinline__ float exp2_native(float x) {
    float r;
    asm("v_exp_f32 %0, %1" : "=v"(r) : "v"(x));
    return r;
}

// ---------------------------------------------------------------- kernel 0
// Pack weights to bf16, n-major.  Even/odd column interleave on wcat (q/k/v/g)
// and woutT.  Wq carries 1/sqrt(32) AND log2(e): QK logits land in the
// log2 domain so attn's softmax uses raw v_exp_f32 (2^x) with no mul.
__global__ void pack_weights(const float* __restrict__ Wq, const float* __restrict__ Wk,
                             const float* __restrict__ Wv, const float* __restrict__ Wb,
                             const float* __restrict__ Wg, const float* __restrict__ Wout,
                             short* __restrict__ wcat, short* __restrict__ woutT) {
    int idx = blockIdx.x * 256 + threadIdx.x;
    if (idx < NCOL * CP) {
        int n = idx >> 7, k = idx & 127;
        float v = 0.f;
        if (n < 512) {
            const float* W = (n < 128) ? Wq : (n < 256) ? Wk : (n < 384) ? Wv : Wg;
            int col = (n & 96) + 2 * (n & 15) + ((n >> 4) & 1);   // even/odd interleave
            v = W[k * 128 + col];
            if (n < 128) v *= 0.17677669529663687f * LOG2E;       // scale + log2e fold
        } else if (n < 516) {
            v = Wb[k * 4 + (n - 512)];
        }
        wcat[n * CP + k] = f2bf(v);
    } else {
        int j = idx - NCOL * CP;
        if (j < 128 * 128) {
            int n = j >> 7, k = j & 127;
            int col = (n & 96) + 2 * (n & 15) + ((n >> 4) & 1);   // same interleave
            woutT[n * 128 + k] = f2bf(Wout[k * 128 + col]);
        }
    }
}

// ---------------------------------------------------------------- kernel 1
// LayerNorm (fp32) + projections (bf16 MFMA).  64 rows/block, 4 waves.
// Wave wv owns all 64 rows x 8 chunks (wave0->q, wave1->k, wave2->v,
// wave3->g + bias).  Results staged per chunk-pair in a wave-private LDS
// tile, then stored as 16B/lane fully contiguous full-line writes.
// bf16 pair conversions via v_cvt_pk_bf16_f32 (packed dword stored whole).
__global__ __launch_bounds__(256, 4)
void ln_proj(const float* __restrict__ pair, const float* __restrict__ gamma,
             const float* __restrict__ beta, const short* __restrict__ wcat,
             short* __restrict__ qt, short* __restrict__ kt,
             short* __restrict__ vt, short* __restrict__ gt,
             float* __restrict__ bt) {
    // LN view: stride 136 (8704 shorts).  Staging view: 4 waves x 2560 shorts.
    __shared__ short pn[10240];
    const int tid = threadIdx.x;
    const int wv = tid >> 6, lane = tid & 63;
    const int quad = lane >> 4, l15 = lane & 15;
    const int r0 = blockIdx.x * 64;
    short* const ST = &pn[wv * 2560];

    float ga0 = gamma[2 * lane], ga1 = gamma[2 * lane + 1];
    float be0 = beta[2 * lane],  be1 = beta[2 * lane + 1];

    #pragma unroll 4
    for (int rr = 0; rr < 16; ++rr) {
        int row = wv * 16 + rr;
        const float* src = pair + (size_t)(r0 + row) * CP + 2 * lane;
        float x0 = src[0], x1 = src[1];
        float s = x0 + x1;
        #pragma unroll
        for (int m = 32; m; m >>= 1) s += __shfl_xor(s, m);
        float mu = s * (1.f / 128.f);
        float d0 = x0 - mu, d1 = x1 - mu;
        float vs = d0 * d0 + d1 * d1;
        #pragma unroll
        for (int m = 32; m; m >>= 1) vs += __shfl_xor(vs, m);
        float rs = rsqrtf(vs * (1.f / 128.f) + 1e-5f);
        unsigned pk = cvtpk(d0 * rs * ga0 + be0, d1 * rs * ga1 + be1);
        *(unsigned*)&pn[row * 136 + 2 * lane] = pk;
    }
    __syncthreads();

    // A-fragments for all 4 row-tiles of this block (64 VGPRs, held in regs)
    short8 af[4][4];
    #pragma unroll
    for (int rt = 0; rt < 4; ++rt)
        #pragma unroll
        for (int s = 0; s < 4; ++s)
            af[rt][s] = *(const short8*)&pn[(rt * 16 + l15) * 136 + s * 32 + quad * 8];
    __syncthreads();   // all waves done reading pn; staging may overwrite it

    short* const dst = (wv == 0) ? qt : (wv == 1) ? kt : (wv == 2) ? vt : gt;

#define LOADB(BUF, CHN) {                                                          \
        int n_ = (CHN) * 16 + l15;                                                 \
        _Pragma("unroll")                                                          \
        for (int s = 0; s < 4; ++s)                                                \
            BUF[s] = *(const short8*)&wcat[(size_t)n_ * CP + s * 32 + quad * 8];   \
    }

    // even chunk: compute + hold accumulators
#define EVEN(BUF) {                                                                \
        _Pragma("unroll")                                                          \
        for (int rt = 0; rt < 4; ++rt) {                                           \
            f32x4 a = {0.f, 0.f, 0.f, 0.f};                                        \
            _Pragma("unroll")                                                      \
            for (int s = 0; s < 4; ++s)                                            \
                a = __builtin_amdgcn_mfma_f32_16x16x32_bf16(af[rt][s], BUF[s], a, 0, 0, 0); \
            accE[rt] = a;                                                          \
        }                                                                          \
    }

    // odd chunk: compute, pack pair into wave-private LDS tile, then store the
    // whole 64x32 head tile as 4 x (64 lanes x 16B) contiguous global writes.
#define ODD(CC, BUF) {                                                             \
        const int chn = wv * 8 + (CC);                                             \
        const int h_ = (chn >> 1) & 3;                                             \
        _Pragma("unroll")                                                          \
        for (int rt = 0; rt < 4; ++rt) {                                           \
            f32x4 a = {0.f, 0.f, 0.f, 0.f};                                        \
            _Pragma("unroll")                                                      \
            for (int s = 0; s < 4; ++s)                                            \
                a = __builtin_amdgcn_mfma_f32_16x16x32_bf16(af[rt][s], BUF[s], a, 0, 0, 0); \
            _Pragma("unroll")                                                      \
            for (int r = 0; r < 4; ++r) {                                          \
                int rowl = rt * 16 + quad * 4 + r;                                 \
                float ve = accE[rt][r], vo = a[r];                                 \
                if (wv == 3) {                                                     \
                    ve = 1.f / (1.f + __expf(-ve));                                \
                    vo = 1.f / (1.f + __expf(-vo));                                \
                }                                                                  \
                *(unsigned*)&ST[rowl * 40 + 2 * l15] = cvtpk(ve, vo);              \
            }                                                                      \
        }                                                                          \
        const size_t hb2 = (size_t)h_ * NT * CHD + (size_t)r0 * CHD;               \
        _Pragma("unroll")                                                          \
        for (int s = 0; s < 4; ++s) {                                              \
            int f = s * 64 + lane;                                                 \
            int row = f >> 2, cs = (f & 3) * 8;                                    \
            short8 v = *(const short8*)&ST[row * 40 + cs];                         \
            *(short8*)(dst + hb2 + (size_t)row * CHD + cs) = v;                    \
        }                                                                          \
    }

    short8 bA[4], bB[4];
    f32x4 accE[4];
    LOADB(bA, wv * 8 + 0)
    LOADB(bB, wv * 8 + 1)
    EVEN(bA) LOADB(bA, wv * 8 + 2)
    ODD(1, bB) LOADB(bB, wv * 8 + 3)
    EVEN(bA) LOADB(bA, wv * 8 + 4)
    ODD(3, bB) LOADB(bB, wv * 8 + 5)
    EVEN(bA) LOADB(bA, wv * 8 + 6)
    ODD(5, bB) LOADB(bB, wv * 8 + 7)
    EVEN(bA) LOADB(bA, wv * 8 + 8)   // wv<3: harmless in-range read; wv3: bias chunk 32
    ODD(7, bB)

    if (wv == 3) {           // bias chunk (chn = 32) is sitting in bA
        #pragma unroll
        for (int rt = 0; rt < 4; ++rt) {
            f32x4 acc = {0.f, 0.f, 0.f, 0.f};
            #pragma unroll
            for (int s = 0; s < 4; ++s)
                acc = __builtin_amdgcn_mfma_f32_16x16x32_bf16(af[rt][s], bA[s], acc, 0, 0, 0);
            if (l15 < 4) {
                #pragma unroll
                for (int r = 0; r < 4; ++r) {
                    int gr = r0 + rt * 16 + quad * 4 + r;
                    bt[l15 * NT + gr] = acc[r];
                }
            }
        }
    }
#undef LOADB
#undef EVEN
#undef ODD
}

// ---------------------------------------------------------------- kernel 1b
// btT[h][k*256+j] = bt[h][j*256+k] * log2(e)   (attn softmax in 2^x domain)
__global__ __launch_bounds__(256)
void bias_T(const float* __restrict__ bt, float* __restrict__ btT) {
    __shared__ float t[64][65];
    int bid = blockIdx.x;
    int h = bid >> 4, tj = (bid >> 2) & 3, tk = bid & 3;
    const float* src = bt + (size_t)h * NT;
    float* dstp = btT + (size_t)h * NT;
    int c = threadIdx.x & 63, r4 = threadIdx.x >> 6;
    #pragma unroll
    for (int rr = 0; rr < 16; ++rr) {
        int r = rr * 4 + r4;
        t[r][c] = src[(size_t)(tj * 64 + r) * 256 + tk * 64 + c];
    }
    __syncthreads();
    #pragma unroll
    for (int rr = 0; rr < 16; ++rr) {
        int k = rr * 4 + r4;
        dstp[(size_t)(tk * 64 + k) * 256 + tj * 64 + c] = t[c][k] * LOG2E;
    }
}

// ---------------------------------------------------------------- kernel 2
// Attention per (i,h).  4 j-tiles of 64 rows; wave owns 16 rows.
// R9 structure (two k-halves, sacc[8], full pl, launch_bounds(256,3)) +
// exp2-domain softmax (Wq/bt pre-scaled by log2e).
// R12 fix of R11's regression: the PV k-axis is PERMUTED consistently on
// both operands -- p(k) = (k>>5)*32 + 2*(k&15) + ((k>>4)&1) -- so the two
// P values a lane holds for (t, t+1) are dword-adjacent in pl.  P-store is
// then ONE cvtpk + ONE dword store per pair (R11 packed across rows and
// had to split the dword back into 2 b16 stores -> extra dependent ops on
// the critical chain -> +5-10us).  Any k-permutation is dot-product
// invariant when applied to both A (pl) and B (vT) operands.
__global__ __launch_bounds__(256, 3)
void attn(const short* __restrict__ qt, const short* __restrict__ kt,
          const short* __restrict__ vt, const short* __restrict__ gt,
          const float* __restrict__ btT, short* __restrict__ og) {
    __shared__ short vT[32 * VTP];    // [c_perm][key_perm]   17152 B
    __shared__ short pl[64 * VTP];    // [j_local][key_perm]  34304 B
    const int tid = threadIdx.x;
    const int h = blockIdx.x >> 8, i = blockIdx.x & 255;
    const int wv = tid >> 6, lane = tid & 63;
    const int quad = lane >> 4, l15 = lane & 15;

    const short* kbase = kt + ((size_t)h * NT + (size_t)i * 256) * CHD;
    const short* vbase = vt + ((size_t)h * NT + (size_t)i * 256) * CHD;
    const short* qbase = qt + ((size_t)h * NT + (size_t)i * 256) * CHD;
    const short* gbase = gt + ((size_t)h * NT + (size_t)i * 256) * CHD;
    const float* btTb = btT + (size_t)h * NT;

    // stage v transposed: channel c -> row (c odd ? 16+c/2 : c/2)  [gate pairing]
    //                     key k    -> col p(k)                      [P pairing]
    for (int g = tid; g < 1024; g += 256) {
        int key = g >> 2, p = g & 3;
        int kp = ((key >> 5) << 5) + 2 * (key & 15) + ((key >> 4) & 1);
        short8 s = *(const short8*)(vbase + key * CHD + p * 8);
        #pragma unroll
        for (int cc = 0; cc < 8; ++cc) {
            int c = p * 8 + cc;
            int row = (c & 1) ? 16 + (c >> 1) : (c >> 1);
            vT[row * VTP + kp] = s[cc];
        }
    }
    __syncthreads();   // the only barrier: vT ready, read-only afterwards

    for (int jt = 0; jt < 4; ++jt) {
        int jbase = jt * 64 + wv * 16;
        short8 aq = *(const short8*)(qbase + (jbase + l15) * CHD + quad * 8);
        // prefetch gate dwords for this jt (consumed at the store)
        unsigned gw0 = *(const unsigned*)(gbase + (size_t)(jbase + quad * 4) * CHD + 2 * l15);
        unsigned gw1 = *(const unsigned*)(gbase + (size_t)(jbase + quad * 4 + 1) * CHD + 2 * l15);
        unsigned gw2 = *(const unsigned*)(gbase + (size_t)(jbase + quad * 4 + 2) * CHD + 2 * l15);
        unsigned gw3 = *(const unsigned*)(gbase + (size_t)(jbase + quad * 4 + 3) * CHD + 2 * l15);

        float sm[4] = {0.f, 0.f, 0.f, 0.f};
        // two k-halves: sacc[8] live at a time (32 regs)
        #pragma unroll
        for (int kh = 0; kh < 2; ++kh) {
            f32x4 sacc[8];
            __builtin_amdgcn_s_setprio(1);
            #pragma unroll
            for (int t = 0; t < 8; ++t) {
                int tt = kh * 8 + t;
                f32x4 c = *(const f32x4*)(btTb + (size_t)(tt * 16 + l15) * 256 + jbase + quad * 4);
                short8 bk = *(const short8*)(kbase + (tt * 16 + l15) * CHD + quad * 8);
                sacc[t] = __builtin_amdgcn_mfma_f32_16x16x32_bf16(aq, bk, c, 0, 0, 0);
            }
            __builtin_amdgcn_s_setprio(0);
            #pragma unroll
            for (int t = 0; t < 8; ++t)
                #pragma unroll
                for (int r = 0; r < 4; ++r) {
                    float e = exp2_native(sacc[t][r]);   // logits already x*log2e
                    sacc[t][r] = e;
                    sm[r] += e;
                }
            // P-half -> LDS: lane's (t, t+1) pair is dword-adjacent at
            // p = (kh*4+u)*32 + 2*l15 under the k-permute.  One cvtpk +
            // one dword store per (u, r).
            #pragma unroll
            for (int u = 0; u < 4; ++u)
                #pragma unroll
                for (int r = 0; r < 4; ++r) {
                    unsigned pk = cvtpk(sacc[2 * u][r], sacc[2 * u + 1][r]);
                    *(unsigned*)&pl[(wv * 16 + quad * 4 + r) * VTP + (kh * 4 + u) * 32 + 2 * l15] = pk;
                }
        }
        #pragma unroll
        for (int m = 1; m < 16; m <<= 1)
            #pragma unroll
            for (int r = 0; r < 4; ++r) sm[r] += __shfl_xor(sm[r], m, 16);
        float inv[4];
        #pragma unroll
        for (int r = 0; r < 4; ++r) inv[r] = 1.f / sm[r];

        // PV (no barrier: same-wave DS ordering covers our writes).
        // Positions are permuted identically in pl and vT -> dot product exact.
        f32x4 oacc[2];
        oacc[0] = f32x4{0.f, 0.f, 0.f, 0.f};
        oacc[1] = f32x4{0.f, 0.f, 0.f, 0.f};
        __builtin_amdgcn_s_setprio(1);
        #pragma unroll
        for (int ks = 0; ks < 8; ++ks) {
            short8 ap = *(const short8*)&pl[(wv * 16 + l15) * VTP + ks * 32 + quad * 8];
            #pragma unroll
            for (int nt = 0; nt < 2; ++nt) {
                short8 bv = *(const short8*)&vT[(nt * 16 + l15) * VTP + ks * 32 + quad * 8];
                oacc[nt] = __builtin_amdgcn_mfma_f32_16x16x32_bf16(ap, bv, oacc[nt], 0, 0, 0);
            }
        }
        __builtin_amdgcn_s_setprio(0);
        // gate + deferred 1/sum + store: cvt_pk packs the og dword directly
        unsigned gws[4] = {gw0, gw1, gw2, gw3};
        #pragma unroll
        for (int r = 0; r < 4; ++r) {
            int j = jbase + quad * 4 + r;
            float g0 = bf2f((short)(gws[r] & 0xffff)) * inv[r];
            float g1 = bf2f((short)(gws[r] >> 16)) * inv[r];
            unsigned pk = cvtpk(oacc[0][r] * g0, oacc[1][r] * g1);
            *(unsigned*)&og[((size_t)i * 256 + j) * CP + h * CHD + 2 * l15] = pk;
        }
    }
}

// ---------------------------------------------------------------- kernel 3
// out = og[65536,128] @ Wout[128,128]  (bf16 MFMA, fp32 out)
// Wave owns one 32-col chunk pair (B loaded once), float2 full-line stores.
__global__ __launch_bounds__(256)
void out_gemm(const short* __restrict__ og, const short* __restrict__ woutT,
              float* __restrict__ out) {
    __shared__ short al[64 * 136];
    const int tid = threadIdx.x;
    const int wv = tid >> 6, lane = tid & 63;
    const int quad = lane >> 4, l15 = lane & 15;
    const int r0 = blockIdx.x * 64;

    for (int g = tid; g < 1024; g += 256) {
        int row = g >> 4, p = g & 15;
        *(short8*)&al[row * 136 + p * 8] = *(const short8*)(og + (size_t)(r0 + row) * CP + p * 8);
    }
    __syncthreads();

    short8 af[4][4];
    #pragma unroll
    for (int rt = 0; rt < 4; ++rt)
        #pragma unroll
        for (int s = 0; s < 4; ++s)
            af[rt][s] = *(const short8*)&al[(rt * 16 + l15) * 136 + s * 32 + quad * 8];

    short8 bE[4], bO[4];
    #pragma unroll
    for (int s = 0; s < 4; ++s) {
        bE[s] = *(const short8*)&woutT[(size_t)(wv * 32 + l15) * 128 + s * 32 + quad * 8];
        bO[s] = *(const short8*)&woutT[(size_t)(wv * 32 + 16 + l15) * 128 + s * 32 + quad * 8];
    }

    #pragma unroll
    for (int rt = 0; rt < 4; ++rt) {
        f32x4 accE = {0.f, 0.f, 0.f, 0.f}, accO = {0.f, 0.f, 0.f, 0.f};
        #pragma unroll
        for (int s = 0; s < 4; ++s) {
            accE = __builtin_amdgcn_mfma_f32_16x16x32_bf16(af[rt][s], bE[s], accE, 0, 0, 0);
            accO = __builtin_amdgcn_mfma_f32_16x16x32_bf16(af[rt][s], bO[s], accO, 0, 0, 0);
        }
        #pragma unroll
        for (int r = 0; r < 4; ++r) {
            f32x2 pk = {accE[r], accO[r]};
            *(f32x2*)&out[(size_t)(r0 + rt * 16 + quad * 4 + r) * CP + wv * 32 + 2 * l15] = pk;
        }
    }
}

// ---------------------------------------------------------------- launch
extern "C" void kernel_launch(void* const* d_in, const int* in_sizes, int n_in,
                              void* d_out, int out_size, void* d_ws, size_t ws_size,
                              hipStream_t stream) {
    (void)in_sizes; (void)n_in; (void)out_size; (void)ws_size;
    const float* pair  = (const float*)d_in[0];
    const float* gamma = (const float*)d_in[1];
    const float* beta  = (const float*)d_in[2];
    const float* Wq    = (const float*)d_in[3];
    const float* Wk    = (const float*)d_in[4];
    const float* Wv    = (const float*)d_in[5];
    const float* Wb    = (const float*)d_in[6];
    const float* Wg    = (const float*)d_in[7];
    const float* Wout  = (const float*)d_in[8];
    float* out = (float*)d_out;

    char* ws = (char*)d_ws;
    const size_t SZ_QKVG = (size_t)NH * NT * CHD * 2;           // 16 MB each
    short* wcat  = (short*)(ws);                                 // 528*128*2 = 135168
    short* woutT = (short*)(ws + 135168);                        // 32768
    short* qt    = (short*)(ws + 167936);
    short* kt    = (short*)(ws + 167936 + SZ_QKVG);
    short* vt    = (short*)(ws + 167936 + 2 * SZ_QKVG);
    short* gt    = (short*)(ws + 167936 + 3 * SZ_QKVG);
    float* bt    = (float*)(ws + 167936 + 4 * SZ_QKVG);          // NH*NT*4 = 1 MB
    float* btT   = (float*)(ws + 167936 + 4 * SZ_QKVG + (size_t)NH * NT * 4);
    short* og    = (short*)(ws + 167936 + 4 * SZ_QKVG + 2 * (size_t)NH * NT * 4);

    hipLaunchKernelGGL(pack_weights, dim3(328), dim3(256), 0, stream,
                       Wq, Wk, Wv, Wb, Wg, Wout, wcat, woutT);
    hipLaunchKernelGGL(ln_proj, dim3(1024), dim3(256), 0, stream,
                       pair, gamma, beta, wcat, qt, kt, vt, gt, bt);
    hipLaunchKernelGGL(bias_T, dim3(64), dim3(256), 0, stream, bt, btT);
    hipLaunchKernelGGL(attn, dim3(1024), dim3(256), 0, stream,
                       qt, kt, vt, gt, btT, og);
    hipLaunchKernelGGL(out_gemm, dim3(1024), dim3(256), 0, stream,
                       og, woutT, out);
}

// Round 14
// 190.715 us; speedup vs baseline: 1.0211x; 1.0211x over previous
//
#include <hip/hip_runtime.h>

#define N_TOK 256
#define CP    128
#define CHD   32
#define NH    4
#define NT    65536   // N_TOK*N_TOK
#define NCOL  528     // 512 (q|k|v|g) + 4 (b) + 12 pad
#define VTP   268     // LDS pitch (shorts): 134 dwords, 134%32=6 -> conflict-free b128/b16
#define LOG2E 1.4426950408889634f

typedef short short8 __attribute__((ext_vector_type(8)));
typedef float f32x4  __attribute__((ext_vector_type(4)));
typedef float f32x2  __attribute__((ext_vector_type(2)));

__device__ __forceinline__ short f2bf(float f) {
    unsigned u = __builtin_bit_cast(unsigned, f);
    u += 0x7fffu + ((u >> 16) & 1u);   // RTNE
    return (short)(u >> 16);
}
__device__ __forceinline__ float bf2f(short s) {
    unsigned u = ((unsigned)(unsigned short)s) << 16;
    return __builtin_bit_cast(float, u);
}

// ---------------------------------------------------------------- kernel 0
// Pack weights to bf16, n-major.  Even/odd column interleave on wcat (q/k/v/g)
// and woutT (consumers pack 2 adjacent output columns per lane -> full-line
// writes).  Wq carries 1/sqrt(32) AND log2(e): QK logits land in the 2^x
// domain so attn's softmax is one v_exp_f32 via __builtin_amdgcn_exp2f
// (compiler intrinsic, schedulable -- R11/R12 lesson: NO inline asm on the
// softmax critical path; R13 lesson: __exp2f is not a device function).
__global__ void pack_weights(const float* __restrict__ Wq, const float* __restrict__ Wk,
                             const float* __restrict__ Wv, const float* __restrict__ Wb,
                             const float* __restrict__ Wg, const float* __restrict__ Wout,
                             short* __restrict__ wcat, short* __restrict__ woutT) {
    int idx = blockIdx.x * 256 + threadIdx.x;
    if (idx < NCOL * CP) {
        int n = idx >> 7, k = idx & 127;
        float v = 0.f;
        if (n < 512) {
            const float* W = (n < 128) ? Wq : (n < 256) ? Wk : (n < 384) ? Wv : Wg;
            int col = (n & 96) + 2 * (n & 15) + ((n >> 4) & 1);   // even/odd interleave
            v = W[k * 128 + col];
            if (n < 128) v *= 0.17677669529663687f * LOG2E;       // scale + log2e fold
        } else if (n < 516) {
            v = Wb[k * 4 + (n - 512)];
        }
        wcat[n * CP + k] = f2bf(v);
    } else {
        int j = idx - NCOL * CP;
        if (j < 128 * 128) {
            int n = j >> 7, k = j & 127;
            int col = (n & 96) + 2 * (n & 15) + ((n >> 4) & 1);   // same interleave
            woutT[n * 128 + k] = f2bf(Wout[k * 128 + col]);
        }
    }
}

// ---------------------------------------------------------------- kernel 1
// LayerNorm (fp32) + projections (bf16 MFMA).  64 rows/block, 4 waves.
// Wave wv owns all 64 rows x 8 chunks (wave0->q, wave1->k, wave2->v,
// wave3->g + bias).  Results staged per chunk-pair in a wave-private LDS
// tile, then stored as 16B/lane fully contiguous full-line writes.
// (R9-exact: no inline-asm conversions.)
__global__ __launch_bounds__(256, 4)
void ln_proj(const float* __restrict__ pair, const float* __restrict__ gamma,
             const float* __restrict__ beta, const short* __restrict__ wcat,
             short* __restrict__ qt, short* __restrict__ kt,
             short* __restrict__ vt, short* __restrict__ gt,
             float* __restrict__ bt) {
    // LN view: stride 136 (8704 shorts).  Staging view: 4 waves x 2560 shorts.
    __shared__ short pn[10240];
    const int tid = threadIdx.x;
    const int wv = tid >> 6, lane = tid & 63;
    const int quad = lane >> 4, l15 = lane & 15;
    const int r0 = blockIdx.x * 64;
    short* const ST = &pn[wv * 2560];

    float ga0 = gamma[2 * lane], ga1 = gamma[2 * lane + 1];
    float be0 = beta[2 * lane],  be1 = beta[2 * lane + 1];

    #pragma unroll 4
    for (int rr = 0; rr < 16; ++rr) {
        int row = wv * 16 + rr;
        const float* src = pair + (size_t)(r0 + row) * CP + 2 * lane;
        float x0 = src[0], x1 = src[1];
        float s = x0 + x1;
        #pragma unroll
        for (int m = 32; m; m >>= 1) s += __shfl_xor(s, m);
        float mu = s * (1.f / 128.f);
        float d0 = x0 - mu, d1 = x1 - mu;
        float vs = d0 * d0 + d1 * d1;
        #pragma unroll
        for (int m = 32; m; m >>= 1) vs += __shfl_xor(vs, m);
        float rs = rsqrtf(vs * (1.f / 128.f) + 1e-5f);
        short y0 = f2bf(d0 * rs * ga0 + be0);
        short y1 = f2bf(d1 * rs * ga1 + be1);
        unsigned pk = ((unsigned)(unsigned short)y0) | (((unsigned)(unsigned short)y1) << 16);
        *(unsigned*)&pn[row * 136 + 2 * lane] = pk;
    }
    __syncthreads();

    // A-fragments for all 4 row-tiles of this block (64 VGPRs, held in regs)
    short8 af[4][4];
    #pragma unroll
    for (int rt = 0; rt < 4; ++rt)
        #pragma unroll
        for (int s = 0; s < 4; ++s)
            af[rt][s] = *(const short8*)&pn[(rt * 16 + l15) * 136 + s * 32 + quad * 8];
    __syncthreads();   // all waves done reading pn; staging may overwrite it

    short* const dst = (wv == 0) ? qt : (wv == 1) ? kt : (wv == 2) ? vt : gt;

#define LOADB(BUF, CHN) {                                                          \
        int n_ = (CHN) * 16 + l15;                                                 \
        _Pragma("unroll")                                                          \
        for (int s = 0; s < 4; ++s)                                                \
            BUF[s] = *(const short8*)&wcat[(size_t)n_ * CP + s * 32 + quad * 8];   \
    }

    // even chunk: compute + hold accumulators
#define EVEN(BUF) {                                                                \
        _Pragma("unroll")                                                          \
        for (int rt = 0; rt < 4; ++rt) {                                           \
            f32x4 a = {0.f, 0.f, 0.f, 0.f};                                        \
            _Pragma("unroll")                                                      \
            for (int s = 0; s < 4; ++s)                                            \
                a = __builtin_amdgcn_mfma_f32_16x16x32_bf16(af[rt][s], BUF[s], a, 0, 0, 0); \
            accE[rt] = a;                                                          \
        }                                                                          \
    }

    // odd chunk: compute, pack pair into wave-private LDS tile, then store the
    // whole 64x32 head tile as 4 x (64 lanes x 16B) contiguous global writes.
#define ODD(CC, BUF) {                                                             \
        const int chn = wv * 8 + (CC);                                             \
        const int h_ = (chn >> 1) & 3;                                             \
        _Pragma("unroll")                                                          \
        for (int rt = 0; rt < 4; ++rt) {                                           \
            f32x4 a = {0.f, 0.f, 0.f, 0.f};                                        \
            _Pragma("unroll")                                                      \
            for (int s = 0; s < 4; ++s)                                            \
                a = __builtin_amdgcn_mfma_f32_16x16x32_bf16(af[rt][s], BUF[s], a, 0, 0, 0); \
            _Pragma("unroll")                                                      \
            for (int r = 0; r < 4; ++r) {                                          \
                int rowl = rt * 16 + quad * 4 + r;                                 \
                float ve = accE[rt][r], vo = a[r];                                 \
                if (wv == 3) {                                                     \
                    ve = 1.f / (1.f + __expf(-ve));                                \
                    vo = 1.f / (1.f + __expf(-vo));                                \
                }                                                                  \
                unsigned pk = ((unsigned)(unsigned short)f2bf(ve))                 \
                            | (((unsigned)(unsigned short)f2bf(vo)) << 16);        \
                *(unsigned*)&ST[rowl * 40 + 2 * l15] = pk;                         \
            }                                                                      \
        }                                                                          \
        const size_t hb2 = (size_t)h_ * NT * CHD + (size_t)r0 * CHD;               \
        _Pragma("unroll")                                                          \
        for (int s = 0; s < 4; ++s) {                                              \
            int f = s * 64 + lane;                                                 \
            int row = f >> 2, cs = (f & 3) * 8;                                    \
            short8 v = *(const short8*)&ST[row * 40 + cs];                         \
            *(short8*)(dst + hb2 + (size_t)row * CHD + cs) = v;                    \
        }                                                                          \
    }

    short8 bA[4], bB[4];
    f32x4 accE[4];
    LOADB(bA, wv * 8 + 0)
    LOADB(bB, wv * 8 + 1)
    EVEN(bA) LOADB(bA, wv * 8 + 2)
    ODD(1, bB) LOADB(bB, wv * 8 + 3)
    EVEN(bA) LOADB(bA, wv * 8 + 4)
    ODD(3, bB) LOADB(bB, wv * 8 + 5)
    EVEN(bA) LOADB(bA, wv * 8 + 6)
    ODD(5, bB) LOADB(bB, wv * 8 + 7)
    EVEN(bA) LOADB(bA, wv * 8 + 8)   // wv<3: harmless in-range read; wv3: bias chunk 32
    ODD(7, bB)

    if (wv == 3) {           // bias chunk (chn = 32) is sitting in bA
        #pragma unroll
        for (int rt = 0; rt < 4; ++rt) {
            f32x4 acc = {0.f, 0.f, 0.f, 0.f};
            #pragma unroll
            for (int s = 0; s < 4; ++s)
                acc = __builtin_amdgcn_mfma_f32_16x16x32_bf16(af[rt][s], bA[s], acc, 0, 0, 0);
            if (l15 < 4) {
                #pragma unroll
                for (int r = 0; r < 4; ++r) {
                    int gr = r0 + rt * 16 + quad * 4 + r;
                    bt[l15 * NT + gr] = acc[r];
                }
            }
        }
    }
#undef LOADB
#undef EVEN
#undef ODD
}

// ---------------------------------------------------------------- kernel 1b
// btT[h][k*256+j] = bt[h][j*256+k] * log2(e)   (attn softmax in 2^x domain)
__global__ __launch_bounds__(256)
void bias_T(const float* __restrict__ bt, float* __restrict__ btT) {
    __shared__ float t[64][65];
    int bid = blockIdx.x;
    int h = bid >> 4, tj = (bid >> 2) & 3, tk = bid & 3;
    const float* src = bt + (size_t)h * NT;
    float* dstp = btT + (size_t)h * NT;
    int c = threadIdx.x & 63, r4 = threadIdx.x >> 6;
    #pragma unroll
    for (int rr = 0; rr < 16; ++rr) {
        int r = rr * 4 + r4;
        t[r][c] = src[(size_t)(tj * 64 + r) * 256 + tk * 64 + c];
    }
    __syncthreads();
    #pragma unroll
    for (int rr = 0; rr < 16; ++rr) {
        int k = rr * 4 + r4;
        dstp[(size_t)(tk * 64 + k) * 256 + tj * 64 + c] = t[c][k] * LOG2E;
    }
}

// ---------------------------------------------------------------- kernel 2
// Attention per (i,h).  4 j-tiles of 64 rows; wave owns 16 rows.
// R9-EXACT structure (best measured: attn 52.7us, total 189.6): two
// k-halves with sacc[8] (32 live regs), full pl (disjoint per-wave rows,
// no WAR reuse), one barrier total, launch_bounds(256,3), no-max softmax
// with deferred normalization, gate dwords prefetched at jt-top, manual
// f2bf conversions (compiler-scheduled; NO inline asm on the critical
// path -- R11/R12 lesson).  Only change vs R9: __builtin_amdgcn_exp2f
// consumes the log2e fold (one v_exp_f32, no preceding v_mul).
__global__ __launch_bounds__(256, 3)
void attn(const short* __restrict__ qt, const short* __restrict__ kt,
          const short* __restrict__ vt, const short* __restrict__ gt,
          const float* __restrict__ btT, short* __restrict__ og) {
    __shared__ short vT[32 * VTP];    // [c_perm][key]   17152 B
    __shared__ short pl[64 * VTP];    // [j_local][key]  34304 B
    const int tid = threadIdx.x;
    const int h = blockIdx.x >> 8, i = blockIdx.x & 255;
    const int wv = tid >> 6, lane = tid & 63;
    const int quad = lane >> 4, l15 = lane & 15;

    const short* kbase = kt + ((size_t)h * NT + (size_t)i * 256) * CHD;
    const short* vbase = vt + ((size_t)h * NT + (size_t)i * 256) * CHD;
    const short* qbase = qt + ((size_t)h * NT + (size_t)i * 256) * CHD;
    const short* gbase = gt + ((size_t)h * NT + (size_t)i * 256) * CHD;
    const float* btTb = btT + (size_t)h * NT;

    // stage v transposed with even/odd permute: col c -> row (c odd ? 16+c/2 : c/2)
    for (int g = tid; g < 1024; g += 256) {
        int key = g >> 2, p = g & 3;
        short8 s = *(const short8*)(vbase + key * CHD + p * 8);
        #pragma unroll
        for (int cc = 0; cc < 8; ++cc) {
            int c = p * 8 + cc;
            int row = (c & 1) ? 16 + (c >> 1) : (c >> 1);
            vT[row * VTP + key] = s[cc];
        }
    }
    __syncthreads();   // the only barrier: vT ready, read-only afterwards

    for (int jt = 0; jt < 4; ++jt) {
        int jbase = jt * 64 + wv * 16;
        short8 aq = *(const short8*)(qbase + (jbase + l15) * CHD + quad * 8);
        // prefetch gate dwords for this jt (consumed at the store)
        unsigned gw0 = *(const unsigned*)(gbase + (size_t)(jbase + quad * 4) * CHD + 2 * l15);
        unsigned gw1 = *(const unsigned*)(gbase + (size_t)(jbase + quad * 4 + 1) * CHD + 2 * l15);
        unsigned gw2 = *(const unsigned*)(gbase + (size_t)(jbase + quad * 4 + 2) * CHD + 2 * l15);
        unsigned gw3 = *(const unsigned*)(gbase + (size_t)(jbase + quad * 4 + 3) * CHD + 2 * l15);

        float sm[4] = {0.f, 0.f, 0.f, 0.f};
        // two k-halves: sacc[8] live at a time (32 regs)
        #pragma unroll
        for (int kh = 0; kh < 2; ++kh) {
            f32x4 sacc[8];
            __builtin_amdgcn_s_setprio(1);
            #pragma unroll
            for (int t = 0; t < 8; ++t) {
                int tt = kh * 8 + t;
                f32x4 c = *(const f32x4*)(btTb + (size_t)(tt * 16 + l15) * 256 + jbase + quad * 4);
                short8 bk = *(const short8*)(kbase + (tt * 16 + l15) * CHD + quad * 8);
                sacc[t] = __builtin_amdgcn_mfma_f32_16x16x32_bf16(aq, bk, c, 0, 0, 0);
            }
            __builtin_amdgcn_s_setprio(0);
            #pragma unroll
            for (int t = 0; t < 8; ++t)
                #pragma unroll
                for (int r = 0; r < 4; ++r) {
                    float e = __builtin_amdgcn_exp2f(sacc[t][r]);   // logits pre-scaled by log2e
                    sacc[t][r] = e;
                    sm[r] += e;
                }
            // P-half -> LDS (own wave's rows; overlaps next half's QK issue)
            #pragma unroll
            for (int t = 0; t < 8; ++t)
                #pragma unroll
                for (int r = 0; r < 4; ++r)
                    pl[(wv * 16 + quad * 4 + r) * VTP + (kh * 8 + t) * 16 + l15] = f2bf(sacc[t][r]);
        }
        #pragma unroll
        for (int m = 1; m < 16; m <<= 1)
            #pragma unroll
            for (int r = 0; r < 4; ++r) sm[r] += __shfl_xor(sm[r], m, 16);
        float inv[4];
        #pragma unroll
        for (int r = 0; r < 4; ++r) inv[r] = 1.f / sm[r];

        // PV (no barrier: same-wave DS ordering covers our writes)
        f32x4 oacc[2];
        oacc[0] = f32x4{0.f, 0.f, 0.f, 0.f};
        oacc[1] = f32x4{0.f, 0.f, 0.f, 0.f};
        __builtin_amdgcn_s_setprio(1);
        #pragma unroll
        for (int ks = 0; ks < 8; ++ks) {
            short8 ap = *(const short8*)&pl[(wv * 16 + l15) * VTP + ks * 32 + quad * 8];
            #pragma unroll
            for (int nt = 0; nt < 2; ++nt) {
                short8 bv = *(const short8*)&vT[(nt * 16 + l15) * VTP + ks * 32 + quad * 8];
                oacc[nt] = __builtin_amdgcn_mfma_f32_16x16x32_bf16(ap, bv, oacc[nt], 0, 0, 0);
            }
        }
        __builtin_amdgcn_s_setprio(0);
        // gate + deferred 1/sum + store: column pair 2*l15(+1) of row j -> dword
        unsigned gws[4] = {gw0, gw1, gw2, gw3};
        #pragma unroll
        for (int r = 0; r < 4; ++r) {
            int j = jbase + quad * 4 + r;
            float g0 = bf2f((short)(gws[r] & 0xffff)) * inv[r];
            float g1 = bf2f((short)(gws[r] >> 16)) * inv[r];
            unsigned pk = ((unsigned)(unsigned short)f2bf(oacc[0][r] * g0))
                        | (((unsigned)(unsigned short)f2bf(oacc[1][r] * g1)) << 16);
            *(unsigned*)&og[((size_t)i * 256 + j) * CP + h * CHD + 2 * l15] = pk;
        }
    }
}

// ---------------------------------------------------------------- kernel 3
// out = og[65536,128] @ Wout[128,128]  (bf16 MFMA, fp32 out)
// Wave owns one 32-col chunk pair (B loaded once), float2 full-line stores.
__global__ __launch_bounds__(256)
void out_gemm(const short* __restrict__ og, const short* __restrict__ woutT,
              float* __restrict__ out) {
    __shared__ short al[64 * 136];
    const int tid = threadIdx.x;
    const int wv = tid >> 6, lane = tid & 63;
    const int quad = lane >> 4, l15 = lane & 15;
    const int r0 = blockIdx.x * 64;

    for (int g = tid; g < 1024; g += 256) {
        int row = g >> 4, p = g & 15;
        *(short8*)&al[row * 136 + p * 8] = *(const short8*)(og + (size_t)(r0 + row) * CP + p * 8);
    }
    __syncthreads();

    short8 af[4][4];
    #pragma unroll
    for (int rt = 0; rt < 4; ++rt)
        #pragma unroll
        for (int s = 0; s < 4; ++s)
            af[rt][s] = *(const short8*)&al[(rt * 16 + l15) * 136 + s * 32 + quad * 8];

    short8 bE[4], bO[4];
    #pragma unroll
    for (int s = 0; s < 4; ++s) {
        bE[s] = *(const short8*)&woutT[(size_t)(wv * 32 + l15) * 128 + s * 32 + quad * 8];
        bO[s] = *(const short8*)&woutT[(size_t)(wv * 32 + 16 + l15) * 128 + s * 32 + quad * 8];
    }

    #pragma unroll
    for (int rt = 0; rt < 4; ++rt) {
        f32x4 accE = {0.f, 0.f, 0.f, 0.f}, accO = {0.f, 0.f, 0.f, 0.f};
        #pragma unroll
        for (int s = 0; s < 4; ++s) {
            accE = __builtin_amdgcn_mfma_f32_16x16x32_bf16(af[rt][s], bE[s], accE, 0, 0, 0);
            accO = __builtin_amdgcn_mfma_f32_16x16x32_bf16(af[rt][s], bO[s], accO, 0, 0, 0);
        }
        #pragma unroll
        for (int r = 0; r < 4; ++r) {
            f32x2 pk = {accE[r], accO[r]};
            *(f32x2*)&out[(size_t)(r0 + rt * 16 + quad * 4 + r) * CP + wv * 32 + 2 * l15] = pk;
        }
    }
}

// ---------------------------------------------------------------- launch
extern "C" void kernel_launch(void* const* d_in, const int* in_sizes, int n_in,
                              void* d_out, int out_size, void* d_ws, size_t ws_size,
                              hipStream_t stream) {
    (void)in_sizes; (void)n_in; (void)out_size; (void)ws_size;
    const float* pair  = (const float*)d_in[0];
    const float* gamma = (const float*)d_in[1];
    const float* beta  = (const float*)d_in[2];
    const float* Wq    = (const float*)d_in[3];
    const float* Wk    = (const float*)d_in[4];
    const float* Wv    = (const float*)d_in[5];
    const float* Wb    = (const float*)d_in[6];
    const float* Wg    = (const float*)d_in[7];
    const float* Wout  = (const float*)d_in[8];
    float* out = (float*)d_out;

    char* ws = (char*)d_ws;
    const size_t SZ_QKVG = (size_t)NH * NT * CHD * 2;           // 16 MB each
    short* wcat  = (short*)(ws);                                 // 528*128*2 = 135168
    short* woutT = (short*)(ws + 135168);                        // 32768
    short* qt    = (short*)(ws + 167936);
    short* kt    = (short*)(ws + 167936 + SZ_QKVG);
    short* vt    = (short*)(ws + 167936 + 2 * SZ_QKVG);
    short* gt    = (short*)(ws + 167936 + 3 * SZ_QKVG);
    float* bt    = (float*)(ws + 167936 + 4 * SZ_QKVG);          // NH*NT*4 = 1 MB
    float* btT   = (float*)(ws + 167936 + 4 * SZ_QKVG + (size_t)NH * NT * 4);
    short* og    = (short*)(ws + 167936 + 4 * SZ_QKVG + 2 * (size_t)NH * NT * 4);

    hipLaunchKernelGGL(pack_weights, dim3(328), dim3(256), 0, stream,
                       Wq, Wk, Wv, Wb, Wg, Wout, wcat, woutT);
    hipLaunchKernelGGL(ln_proj, dim3(1024), dim3(256), 0, stream,
                       pair, gamma, beta, wcat, qt, kt, vt, gt, bt);
    hipLaunchKernelGGL(bias_T, dim3(64), dim3(256), 0, stream, bt, btT);
    hipLaunchKernelGGL(attn, dim3(1024), dim3(256), 0, stream,
                       qt, kt, vt, gt, btT, og);
    hipLaunchKernelGGL(out_gemm, dim3(1024), dim3(256), 0, stream,
                       og, woutT, out);
}

// Round 15
// 187.703 us; speedup vs baseline: 1.0375x; 1.0161x over previous
//
#include <hip/hip_runtime.h>

#define N_TOK 256
#define CP    128
#define CHD   32
#define NH    4
#define NT    65536   // N_TOK*N_TOK
#define NCOL  528     // 512 (q|k|v|g) + 4 (b) + 12 pad
#define VTP   268     // LDS pitch (shorts): 134 dwords, 134%32=6 -> conflict-free b128/b16
#define LOG2E 1.4426950408889634f

typedef short short8 __attribute__((ext_vector_type(8)));
typedef float f32x4  __attribute__((ext_vector_type(4)));
typedef float f32x2  __attribute__((ext_vector_type(2)));

__device__ __forceinline__ short f2bf(float f) {
    unsigned u = __builtin_bit_cast(unsigned, f);
    u += 0x7fffu + ((u >> 16) & 1u);   // RTNE
    return (short)(u >> 16);
}
__device__ __forceinline__ float bf2f(short s) {
    unsigned u = ((unsigned)(unsigned short)s) << 16;
    return __builtin_bit_cast(float, u);
}

// ---------------------------------------------------------------- kernel 0
// Pack weights to bf16, n-major.  Even/odd column interleave on wcat (q/k/v/g)
// and woutT (consumers pack 2 adjacent output columns per lane -> full-line
// writes).  Wq carries 1/sqrt(32)*log2(e); Wb carries log2(e): QK logits and
// bias land in the 2^x domain so attn's softmax is one v_exp_f32
// (__builtin_amdgcn_exp2f -- compiler intrinsic, schedulable).
__global__ void pack_weights(const float* __restrict__ Wq, const float* __restrict__ Wk,
                             const float* __restrict__ Wv, const float* __restrict__ Wb,
                             const float* __restrict__ Wg, const float* __restrict__ Wout,
                             short* __restrict__ wcat, short* __restrict__ woutT) {
    int idx = blockIdx.x * 256 + threadIdx.x;
    if (idx < NCOL * CP) {
        int n = idx >> 7, k = idx & 127;
        float v = 0.f;
        if (n < 512) {
            const float* W = (n < 128) ? Wq : (n < 256) ? Wk : (n < 384) ? Wv : Wg;
            int col = (n & 96) + 2 * (n & 15) + ((n >> 4) & 1);   // even/odd interleave
            v = W[k * 128 + col];
            if (n < 128) v *= 0.17677669529663687f * LOG2E;       // scale + log2e fold
        } else if (n < 516) {
            v = Wb[k * 4 + (n - 512)] * LOG2E;                    // log2e fold (bias)
        }
        wcat[n * CP + k] = f2bf(v);
    } else {
        int j = idx - NCOL * CP;
        if (j < 128 * 128) {
            int n = j >> 7, k = j & 127;
            int col = (n & 96) + 2 * (n & 15) + ((n >> 4) & 1);   // same interleave
            woutT[n * 128 + k] = f2bf(Wout[k * 128 + col]);
        }
    }
}

// ---------------------------------------------------------------- kernel 1
// LayerNorm (fp32) + projections (bf16 MFMA).  64 rows/block, 4 waves.
// Wave wv owns all 64 rows x 8 chunks (wave0->q, wave1->k, wave2->v,
// wave3->g + bias).  Results staged per chunk-pair in a wave-private LDS
// tile, then stored as 16B/lane fully contiguous full-line writes.
// R15: the bias chunk is written DIRECTLY TRANSPOSED to btT[h][k*256+j]
// (within a block j = r0>>8 is constant, k walks 64 consecutive values) --
// this deletes the bias_T kernel (one dispatch + drain + ramp) and bt's
// 1MB write/read round-trip.  Scattered dword stores: 1MB total, line
// amplification ~16x = ~16MB extra HBM write, hidden in ln_proj's slack.
__global__ __launch_bounds__(256, 4)
void ln_proj(const float* __restrict__ pair, const float* __restrict__ gamma,
             const float* __restrict__ beta, const short* __restrict__ wcat,
             short* __restrict__ qt, short* __restrict__ kt,
             short* __restrict__ vt, short* __restrict__ gt,
             float* __restrict__ btT) {
    // LN view: stride 136 (8704 shorts).  Staging view: 4 waves x 2560 shorts.
    __shared__ short pn[10240];
    const int tid = threadIdx.x;
    const int wv = tid >> 6, lane = tid & 63;
    const int quad = lane >> 4, l15 = lane & 15;
    const int r0 = blockIdx.x * 64;
    short* const ST = &pn[wv * 2560];

    float ga0 = gamma[2 * lane], ga1 = gamma[2 * lane + 1];
    float be0 = beta[2 * lane],  be1 = beta[2 * lane + 1];

    #pragma unroll 4
    for (int rr = 0; rr < 16; ++rr) {
        int row = wv * 16 + rr;
        const float* src = pair + (size_t)(r0 + row) * CP + 2 * lane;
        float x0 = src[0], x1 = src[1];
        float s = x0 + x1;
        #pragma unroll
        for (int m = 32; m; m >>= 1) s += __shfl_xor(s, m);
        float mu = s * (1.f / 128.f);
        float d0 = x0 - mu, d1 = x1 - mu;
        float vs = d0 * d0 + d1 * d1;
        #pragma unroll
        for (int m = 32; m; m >>= 1) vs += __shfl_xor(vs, m);
        float rs = rsqrtf(vs * (1.f / 128.f) + 1e-5f);
        short y0 = f2bf(d0 * rs * ga0 + be0);
        short y1 = f2bf(d1 * rs * ga1 + be1);
        unsigned pk = ((unsigned)(unsigned short)y0) | (((unsigned)(unsigned short)y1) << 16);
        *(unsigned*)&pn[row * 136 + 2 * lane] = pk;
    }
    __syncthreads();

    // A-fragments for all 4 row-tiles of this block (64 VGPRs, held in regs)
    short8 af[4][4];
    #pragma unroll
    for (int rt = 0; rt < 4; ++rt)
        #pragma unroll
        for (int s = 0; s < 4; ++s)
            af[rt][s] = *(const short8*)&pn[(rt * 16 + l15) * 136 + s * 32 + quad * 8];
    __syncthreads();   // all waves done reading pn; staging may overwrite it

    short* const dst = (wv == 0) ? qt : (wv == 1) ? kt : (wv == 2) ? vt : gt;

#define LOADB(BUF, CHN) {                                                          \
        int n_ = (CHN) * 16 + l15;                                                 \
        _Pragma("unroll")                                                          \
        for (int s = 0; s < 4; ++s)                                                \
            BUF[s] = *(const short8*)&wcat[(size_t)n_ * CP + s * 32 + quad * 8];   \
    }

    // even chunk: compute + hold accumulators
#define EVEN(BUF) {                                                                \
        _Pragma("unroll")                                                          \
        for (int rt = 0; rt < 4; ++rt) {                                           \
            f32x4 a = {0.f, 0.f, 0.f, 0.f};                                        \
            _Pragma("unroll")                                                      \
            for (int s = 0; s < 4; ++s)                                            \
                a = __builtin_amdgcn_mfma_f32_16x16x32_bf16(af[rt][s], BUF[s], a, 0, 0, 0); \
            accE[rt] = a;                                                          \
        }                                                                          \
    }

    // odd chunk: compute, pack pair into wave-private LDS tile, then store the
    // whole 64x32 head tile as 4 x (64 lanes x 16B) contiguous global writes.
#define ODD(CC, BUF) {                                                             \
        const int chn = wv * 8 + (CC);                                             \
        const int h_ = (chn >> 1) & 3;                                             \
        _Pragma("unroll")                                                          \
        for (int rt = 0; rt < 4; ++rt) {                                           \
            f32x4 a = {0.f, 0.f, 0.f, 0.f};                                        \
            _Pragma("unroll")                                                      \
            for (int s = 0; s < 4; ++s)                                            \
                a = __builtin_amdgcn_mfma_f32_16x16x32_bf16(af[rt][s], BUF[s], a, 0, 0, 0); \
            _Pragma("unroll")                                                      \
            for (int r = 0; r < 4; ++r) {                                          \
                int rowl = rt * 16 + quad * 4 + r;                                 \
                float ve = accE[rt][r], vo = a[r];                                 \
                if (wv == 3) {                                                     \
                    ve = 1.f / (1.f + __expf(-ve));                                \
                    vo = 1.f / (1.f + __expf(-vo));                                \
                }                                                                  \
                unsigned pk = ((unsigned)(unsigned short)f2bf(ve))                 \
                            | (((unsigned)(unsigned short)f2bf(vo)) << 16);        \
                *(unsigned*)&ST[rowl * 40 + 2 * l15] = pk;                         \
            }                                                                      \
        }                                                                          \
        const size_t hb2 = (size_t)h_ * NT * CHD + (size_t)r0 * CHD;               \
        _Pragma("unroll")                                                          \
        for (int s = 0; s < 4; ++s) {                                              \
            int f = s * 64 + lane;                                                 \
            int row = f >> 2, cs = (f & 3) * 8;                                    \
            short8 v = *(const short8*)&ST[row * 40 + cs];                         \
            *(short8*)(dst + hb2 + (size_t)row * CHD + cs) = v;                    \
        }                                                                          \
    }

    short8 bA[4], bB[4];
    f32x4 accE[4];
    LOADB(bA, wv * 8 + 0)
    LOADB(bB, wv * 8 + 1)
    EVEN(bA) LOADB(bA, wv * 8 + 2)
    ODD(1, bB) LOADB(bB, wv * 8 + 3)
    EVEN(bA) LOADB(bA, wv * 8 + 4)
    ODD(3, bB) LOADB(bB, wv * 8 + 5)
    EVEN(bA) LOADB(bA, wv * 8 + 6)
    ODD(5, bB) LOADB(bB, wv * 8 + 7)
    EVEN(bA) LOADB(bA, wv * 8 + 8)   // wv<3: harmless in-range read; wv3: bias chunk 32
    ODD(7, bB)

    if (wv == 3) {           // bias chunk (chn = 32, log2e pre-folded) in bA
        const int j0 = r0 >> 8;          // first-token index (constant per block)
        const int k0 = r0 & 255;         // second-token base
        #pragma unroll
        for (int rt = 0; rt < 4; ++rt) {
            f32x4 acc = {0.f, 0.f, 0.f, 0.f};
            #pragma unroll
            for (int s = 0; s < 4; ++s)
                acc = __builtin_amdgcn_mfma_f32_16x16x32_bf16(af[rt][s], bA[s], acc, 0, 0, 0);
            if (l15 < 4) {
                #pragma unroll
                for (int r = 0; r < 4; ++r) {
                    int k = k0 + rt * 16 + quad * 4 + r;
                    btT[(size_t)l15 * NT + (size_t)k * 256 + j0] = acc[r];   // transposed
                }
            }
        }
    }
#undef LOADB
#undef EVEN
#undef ODD
}

// ---------------------------------------------------------------- kernel 2
// Attention per (i,h).  4 j-tiles of 64 rows; wave owns 16 rows.
// R9-EXACT structure (best measured: attn 52.7us): two k-halves with
// sacc[8] (32 live regs), full pl (disjoint per-wave rows, no WAR reuse),
// one barrier total, launch_bounds(256,3), no-max softmax with deferred
// normalization, gate dwords prefetched at jt-top, manual f2bf conversions
// (compiler-scheduled; NO inline asm on the critical path), exp2-domain
// softmax via __builtin_amdgcn_exp2f (logits pre-scaled by log2e).
__global__ __launch_bounds__(256, 3)
void attn(const short* __restrict__ qt, const short* __restrict__ kt,
          const short* __restrict__ vt, const short* __restrict__ gt,
          const float* __restrict__ btT, short* __restrict__ og) {
    __shared__ short vT[32 * VTP];    // [c_perm][key]   17152 B
    __shared__ short pl[64 * VTP];    // [j_local][key]  34304 B
    const int tid = threadIdx.x;
    const int h = blockIdx.x >> 8, i = blockIdx.x & 255;
    const int wv = tid >> 6, lane = tid & 63;
    const int quad = lane >> 4, l15 = lane & 15;

    const short* kbase = kt + ((size_t)h * NT + (size_t)i * 256) * CHD;
    const short* vbase = vt + ((size_t)h * NT + (size_t)i * 256) * CHD;
    const short* qbase = qt + ((size_t)h * NT + (size_t)i * 256) * CHD;
    const short* gbase = gt + ((size_t)h * NT + (size_t)i * 256) * CHD;
    const float* btTb = btT + (size_t)h * NT;

    // stage v transposed with even/odd permute: col c -> row (c odd ? 16+c/2 : c/2)
    for (int g = tid; g < 1024; g += 256) {
        int key = g >> 2, p = g & 3;
        short8 s = *(const short8*)(vbase + key * CHD + p * 8);
        #pragma unroll
        for (int cc = 0; cc < 8; ++cc) {
            int c = p * 8 + cc;
            int row = (c & 1) ? 16 + (c >> 1) : (c >> 1);
            vT[row * VTP + key] = s[cc];
        }
    }
    __syncthreads();   // the only barrier: vT ready, read-only afterwards

    for (int jt = 0; jt < 4; ++jt) {
        int jbase = jt * 64 + wv * 16;
        short8 aq = *(const short8*)(qbase + (jbase + l15) * CHD + quad * 8);
        // prefetch gate dwords for this jt (consumed at the store)
        unsigned gw0 = *(const unsigned*)(gbase + (size_t)(jbase + quad * 4) * CHD + 2 * l15);
        unsigned gw1 = *(const unsigned*)(gbase + (size_t)(jbase + quad * 4 + 1) * CHD + 2 * l15);
        unsigned gw2 = *(const unsigned*)(gbase + (size_t)(jbase + quad * 4 + 2) * CHD + 2 * l15);
        unsigned gw3 = *(const unsigned*)(gbase + (size_t)(jbase + quad * 4 + 3) * CHD + 2 * l15);

        float sm[4] = {0.f, 0.f, 0.f, 0.f};
        // two k-halves: sacc[8] live at a time (32 regs)
        #pragma unroll
        for (int kh = 0; kh < 2; ++kh) {
            f32x4 sacc[8];
            __builtin_amdgcn_s_setprio(1);
            #pragma unroll
            for (int t = 0; t < 8; ++t) {
                int tt = kh * 8 + t;
                f32x4 c = *(const f32x4*)(btTb + (size_t)(tt * 16 + l15) * 256 + jbase + quad * 4);
                short8 bk = *(const short8*)(kbase + (tt * 16 + l15) * CHD + quad * 8);
                sacc[t] = __builtin_amdgcn_mfma_f32_16x16x32_bf16(aq, bk, c, 0, 0, 0);
            }
            __builtin_amdgcn_s_setprio(0);
            #pragma unroll
            for (int t = 0; t < 8; ++t)
                #pragma unroll
                for (int r = 0; r < 4; ++r) {
                    float e = __builtin_amdgcn_exp2f(sacc[t][r]);   // logits pre-scaled by log2e
                    sacc[t][r] = e;
                    sm[r] += e;
                }
            // P-half -> LDS (own wave's rows; overlaps next half's QK issue)
            #pragma unroll
            for (int t = 0; t < 8; ++t)
                #pragma unroll
                for (int r = 0; r < 4; ++r)
                    pl[(wv * 16 + quad * 4 + r) * VTP + (kh * 8 + t) * 16 + l15] = f2bf(sacc[t][r]);
        }
        #pragma unroll
        for (int m = 1; m < 16; m <<= 1)
            #pragma unroll
            for (int r = 0; r < 4; ++r) sm[r] += __shfl_xor(sm[r], m, 16);
        float inv[4];
        #pragma unroll
        for (int r = 0; r < 4; ++r) inv[r] = 1.f / sm[r];

        // PV (no barrier: same-wave DS ordering covers our writes)
        f32x4 oacc[2];
        oacc[0] = f32x4{0.f, 0.f, 0.f, 0.f};
        oacc[1] = f32x4{0.f, 0.f, 0.f, 0.f};
        __builtin_amdgcn_s_setprio(1);
        #pragma unroll
        for (int ks = 0; ks < 8; ++ks) {
            short8 ap = *(const short8*)&pl[(wv * 16 + l15) * VTP + ks * 32 + quad * 8];
            #pragma unroll
            for (int nt = 0; nt < 2; ++nt) {
                short8 bv = *(const short8*)&vT[(nt * 16 + l15) * VTP + ks * 32 + quad * 8];
                oacc[nt] = __builtin_amdgcn_mfma_f32_16x16x32_bf16(ap, bv, oacc[nt], 0, 0, 0);
            }
        }
        __builtin_amdgcn_s_setprio(0);
        // gate + deferred 1/sum + store: column pair 2*l15(+1) of row j -> dword
        unsigned gws[4] = {gw0, gw1, gw2, gw3};
        #pragma unroll
        for (int r = 0; r < 4; ++r) {
            int j = jbase + quad * 4 + r;
            float g0 = bf2f((short)(gws[r] & 0xffff)) * inv[r];
            float g1 = bf2f((short)(gws[r] >> 16)) * inv[r];
            unsigned pk = ((unsigned)(unsigned short)f2bf(oacc[0][r] * g0))
                        | (((unsigned)(unsigned short)f2bf(oacc[1][r] * g1)) << 16);
            *(unsigned*)&og[((size_t)i * 256 + j) * CP + h * CHD + 2 * l15] = pk;
        }
    }
}

// ---------------------------------------------------------------- kernel 3
// out = og[65536,128] @ Wout[128,128]  (bf16 MFMA, fp32 out)
// Wave owns one 32-col chunk pair (B loaded once), float2 full-line stores.
__global__ __launch_bounds__(256)
void out_gemm(const short* __restrict__ og, const short* __restrict__ woutT,
              float* __restrict__ out) {
    __shared__ short al[64 * 136];
    const int tid = threadIdx.x;
    const int wv = tid >> 6, lane = tid & 63;
    const int quad = lane >> 4, l15 = lane & 15;
    const int r0 = blockIdx.x * 64;

    for (int g = tid; g < 1024; g += 256) {
        int row = g >> 4, p = g & 15;
        *(short8*)&al[row * 136 + p * 8] = *(const short8*)(og + (size_t)(r0 + row) * CP + p * 8);
    }
    __syncthreads();

    short8 af[4][4];
    #pragma unroll
    for (int rt = 0; rt < 4; ++rt)
        #pragma unroll
        for (int s = 0; s < 4; ++s)
            af[rt][s] = *(const short8*)&al[(rt * 16 + l15) * 136 + s * 32 + quad * 8];

    short8 bE[4], bO[4];
    #pragma unroll
    for (int s = 0; s < 4; ++s) {
        bE[s] = *(const short8*)&woutT[(size_t)(wv * 32 + l15) * 128 + s * 32 + quad * 8];
        bO[s] = *(const short8*)&woutT[(size_t)(wv * 32 + 16 + l15) * 128 + s * 32 + quad * 8];
    }

    #pragma unroll
    for (int rt = 0; rt < 4; ++rt) {
        f32x4 accE = {0.f, 0.f, 0.f, 0.f}, accO = {0.f, 0.f, 0.f, 0.f};
        #pragma unroll
        for (int s = 0; s < 4; ++s) {
            accE = __builtin_amdgcn_mfma_f32_16x16x32_bf16(af[rt][s], bE[s], accE, 0, 0, 0);
            accO = __builtin_amdgcn_mfma_f32_16x16x32_bf16(af[rt][s], bO[s], accO, 0, 0, 0);
        }
        #pragma unroll
        for (int r = 0; r < 4; ++r) {
            f32x2 pk = {accE[r], accO[r]};
            *(f32x2*)&out[(size_t)(r0 + rt * 16 + quad * 4 + r) * CP + wv * 32 + 2 * l15] = pk;
        }
    }
}

// ---------------------------------------------------------------- launch
extern "C" void kernel_launch(void* const* d_in, const int* in_sizes, int n_in,
                              void* d_out, int out_size, void* d_ws, size_t ws_size,
                              hipStream_t stream) {
    (void)in_sizes; (void)n_in; (void)out_size; (void)ws_size;
    const float* pair  = (const float*)d_in[0];
    const float* gamma = (const float*)d_in[1];
    const float* beta  = (const float*)d_in[2];
    const float* Wq    = (const float*)d_in[3];
    const float* Wk    = (const float*)d_in[4];
    const float* Wv    = (const float*)d_in[5];
    const float* Wb    = (const float*)d_in[6];
    const float* Wg    = (const float*)d_in[7];
    const float* Wout  = (const float*)d_in[8];
    float* out = (float*)d_out;

    char* ws = (char*)d_ws;
    const size_t SZ_QKVG = (size_t)NH * NT * CHD * 2;           // 16 MB each
    short* wcat  = (short*)(ws);                                 // 528*128*2 = 135168
    short* woutT = (short*)(ws + 135168);                        // 32768
    short* qt    = (short*)(ws + 167936);
    short* kt    = (short*)(ws + 167936 + SZ_QKVG);
    short* vt    = (short*)(ws + 167936 + 2 * SZ_QKVG);
    short* gt    = (short*)(ws + 167936 + 3 * SZ_QKVG);
    float* btT   = (float*)(ws + 167936 + 4 * SZ_QKVG);          // NH*NT*4 = 1 MB
    short* og    = (short*)(ws + 167936 + 4 * SZ_QKVG + (size_t)NH * NT * 4);

    hipLaunchKernelGGL(pack_weights, dim3(328), dim3(256), 0, stream,
                       Wq, Wk, Wv, Wb, Wg, Wout, wcat, woutT);
    hipLaunchKernelGGL(ln_proj, dim3(1024), dim3(256), 0, stream,
                       pair, gamma, beta, wcat, qt, kt, vt, gt, btT);
    hipLaunchKernelGGL(attn, dim3(1024), dim3(256), 0, stream,
                       qt, kt, vt, gt, btT, og);
    hipLaunchKernelGGL(out_gemm, dim3(1024), dim3(256), 0, stream,
                       og, woutT, out);
}

// Round 16
// 186.422 us; speedup vs baseline: 1.0446x; 1.0069x over previous
//
#include <hip/hip_runtime.h>

#define N_TOK 256
#define CP    128
#define CHD   32
#define NH    4
#define NT    65536   // N_TOK*N_TOK
#define NCOL  528     // 512 (q|k|v|g) + 4 (b) + 12 pad
#define VTP   268     // LDS pitch (shorts): 134 dwords, 134%32=6 -> conflict-free b128/b16
#define LOG2E 1.4426950408889634f

typedef short short8 __attribute__((ext_vector_type(8)));
typedef float f32x4  __attribute__((ext_vector_type(4)));
typedef float f32x2  __attribute__((ext_vector_type(2)));

__device__ __forceinline__ short f2bf(float f) {
    unsigned u = __builtin_bit_cast(unsigned, f);
    u += 0x7fffu + ((u >> 16) & 1u);   // RTNE
    return (short)(u >> 16);
}
__device__ __forceinline__ float bf2f(short s) {
    unsigned u = ((unsigned)(unsigned short)s) << 16;
    return __builtin_bit_cast(float, u);
}

// ---------------------------------------------------------------- kernel 0
// Pack weights to bf16, n-major.  Even/odd column interleave on wcat (q/k/v/g)
// and woutT (consumers pack 2 adjacent output columns per lane -> full-line
// writes).  Wq carries 1/sqrt(32)*log2(e); Wb carries log2(e): QK logits and
// bias land in the 2^x domain so attn's softmax is one v_exp_f32
// (__builtin_amdgcn_exp2f -- compiler intrinsic, schedulable).
__global__ void pack_weights(const float* __restrict__ Wq, const float* __restrict__ Wk,
                             const float* __restrict__ Wv, const float* __restrict__ Wb,
                             const float* __restrict__ Wg, const float* __restrict__ Wout,
                             short* __restrict__ wcat, short* __restrict__ woutT) {
    int idx = blockIdx.x * 256 + threadIdx.x;
    if (idx < NCOL * CP) {
        int n = idx >> 7, k = idx & 127;
        float v = 0.f;
        if (n < 512) {
            const float* W = (n < 128) ? Wq : (n < 256) ? Wk : (n < 384) ? Wv : Wg;
            int col = (n & 96) + 2 * (n & 15) + ((n >> 4) & 1);   // even/odd interleave
            v = W[k * 128 + col];
            if (n < 128) v *= 0.17677669529663687f * LOG2E;       // scale + log2e fold
        } else if (n < 516) {
            v = Wb[k * 4 + (n - 512)] * LOG2E;                    // log2e fold (bias)
        }
        wcat[n * CP + k] = f2bf(v);
    } else {
        int j = idx - NCOL * CP;
        if (j < 128 * 128) {
            int n = j >> 7, k = j & 127;
            int col = (n & 96) + 2 * (n & 15) + ((n >> 4) & 1);   // same interleave
            woutT[n * 128 + k] = f2bf(Wout[k * 128 + col]);
        }
    }
}

// ---------------------------------------------------------------- kernel 1
// LayerNorm (fp32) + projections (bf16 MFMA).  64 rows/block, 4 waves.
// Wave wv owns all 64 rows x 8 chunks (wave0->q, wave1->k, wave2->v,
// wave3->g + bias).  Results staged per chunk-pair in a wave-private LDS
// tile, then stored as 16B/lane fully contiguous full-line writes.
// Bias chunk written directly transposed to btT[h][k*256+j] (bias_T kernel
// deleted in R15; -3us net).
__global__ __launch_bounds__(256, 4)
void ln_proj(const float* __restrict__ pair, const float* __restrict__ gamma,
             const float* __restrict__ beta, const short* __restrict__ wcat,
             short* __restrict__ qt, short* __restrict__ kt,
             short* __restrict__ vt, short* __restrict__ gt,
             float* __restrict__ btT) {
    // LN view: stride 136 (8704 shorts).  Staging view: 4 waves x 2560 shorts.
    __shared__ short pn[10240];
    const int tid = threadIdx.x;
    const int wv = tid >> 6, lane = tid & 63;
    const int quad = lane >> 4, l15 = lane & 15;
    const int r0 = blockIdx.x * 64;
    short* const ST = &pn[wv * 2560];

    float ga0 = gamma[2 * lane], ga1 = gamma[2 * lane + 1];
    float be0 = beta[2 * lane],  be1 = beta[2 * lane + 1];

    #pragma unroll 4
    for (int rr = 0; rr < 16; ++rr) {
        int row = wv * 16 + rr;
        const float* src = pair + (size_t)(r0 + row) * CP + 2 * lane;
        float x0 = src[0], x1 = src[1];
        float s = x0 + x1;
        #pragma unroll
        for (int m = 32; m; m >>= 1) s += __shfl_xor(s, m);
        float mu = s * (1.f / 128.f);
        float d0 = x0 - mu, d1 = x1 - mu;
        float vs = d0 * d0 + d1 * d1;
        #pragma unroll
        for (int m = 32; m; m >>= 1) vs += __shfl_xor(vs, m);
        float rs = rsqrtf(vs * (1.f / 128.f) + 1e-5f);
        short y0 = f2bf(d0 * rs * ga0 + be0);
        short y1 = f2bf(d1 * rs * ga1 + be1);
        unsigned pk = ((unsigned)(unsigned short)y0) | (((unsigned)(unsigned short)y1) << 16);
        *(unsigned*)&pn[row * 136 + 2 * lane] = pk;
    }
    __syncthreads();

    // A-fragments for all 4 row-tiles of this block (64 VGPRs, held in regs)
    short8 af[4][4];
    #pragma unroll
    for (int rt = 0; rt < 4; ++rt)
        #pragma unroll
        for (int s = 0; s < 4; ++s)
            af[rt][s] = *(const short8*)&pn[(rt * 16 + l15) * 136 + s * 32 + quad * 8];
    __syncthreads();   // all waves done reading pn; staging may overwrite it

    short* const dst = (wv == 0) ? qt : (wv == 1) ? kt : (wv == 2) ? vt : gt;

#define LOADB(BUF, CHN) {                                                          \
        int n_ = (CHN) * 16 + l15;                                                 \
        _Pragma("unroll")                                                          \
        for (int s = 0; s < 4; ++s)                                                \
            BUF[s] = *(const short8*)&wcat[(size_t)n_ * CP + s * 32 + quad * 8];   \
    }

    // even chunk: compute + hold accumulators
#define EVEN(BUF) {                                                                \
        _Pragma("unroll")                                                          \
        for (int rt = 0; rt < 4; ++rt) {                                           \
            f32x4 a = {0.f, 0.f, 0.f, 0.f};                                        \
            _Pragma("unroll")                                                      \
            for (int s = 0; s < 4; ++s)                                            \
                a = __builtin_amdgcn_mfma_f32_16x16x32_bf16(af[rt][s], BUF[s], a, 0, 0, 0); \
            accE[rt] = a;                                                          \
        }                                                                          \
    }

    // odd chunk: compute, pack pair into wave-private LDS tile, then store the
    // whole 64x32 head tile as 4 x (64 lanes x 16B) contiguous global writes.
#define ODD(CC, BUF) {                                                             \
        const int chn = wv * 8 + (CC);                                             \
        const int h_ = (chn >> 1) & 3;                                             \
        _Pragma("unroll")                                                          \
        for (int rt = 0; rt < 4; ++rt) {                                           \
            f32x4 a = {0.f, 0.f, 0.f, 0.f};                                        \
            _Pragma("unroll")                                                      \
            for (int s = 0; s < 4; ++s)                                            \
                a = __builtin_amdgcn_mfma_f32_16x16x32_bf16(af[rt][s], BUF[s], a, 0, 0, 0); \
            _Pragma("unroll")                                                      \
            for (int r = 0; r < 4; ++r) {                                          \
                int rowl = rt * 16 + quad * 4 + r;                                 \
                float ve = accE[rt][r], vo = a[r];                                 \
                if (wv == 3) {                                                     \
                    ve = 1.f / (1.f + __expf(-ve));                                \
                    vo = 1.f / (1.f + __expf(-vo));                                \
                }                                                                  \
                unsigned pk = ((unsigned)(unsigned short)f2bf(ve))                 \
                            | (((unsigned)(unsigned short)f2bf(vo)) << 16);        \
                *(unsigned*)&ST[rowl * 40 + 2 * l15] = pk;                         \
            }                                                                      \
        }                                                                          \
        const size_t hb2 = (size_t)h_ * NT * CHD + (size_t)r0 * CHD;               \
        _Pragma("unroll")                                                          \
        for (int s = 0; s < 4; ++s) {                                              \
            int f = s * 64 + lane;                                                 \
            int row = f >> 2, cs = (f & 3) * 8;                                    \
            short8 v = *(const short8*)&ST[row * 40 + cs];                         \
            *(short8*)(dst + hb2 + (size_t)row * CHD + cs) = v;                    \
        }                                                                          \
    }

    short8 bA[4], bB[4];
    f32x4 accE[4];
    LOADB(bA, wv * 8 + 0)
    LOADB(bB, wv * 8 + 1)
    EVEN(bA) LOADB(bA, wv * 8 + 2)
    ODD(1, bB) LOADB(bB, wv * 8 + 3)
    EVEN(bA) LOADB(bA, wv * 8 + 4)
    ODD(3, bB) LOADB(bB, wv * 8 + 5)
    EVEN(bA) LOADB(bA, wv * 8 + 6)
    ODD(5, bB) LOADB(bB, wv * 8 + 7)
    EVEN(bA) LOADB(bA, wv * 8 + 8)   // wv<3: harmless in-range read; wv3: bias chunk 32
    ODD(7, bB)

    if (wv == 3) {           // bias chunk (chn = 32, log2e pre-folded) in bA
        const int j0 = r0 >> 8;          // first-token index (constant per block)
        const int k0 = r0 & 255;         // second-token base
        #pragma unroll
        for (int rt = 0; rt < 4; ++rt) {
            f32x4 acc = {0.f, 0.f, 0.f, 0.f};
            #pragma unroll
            for (int s = 0; s < 4; ++s)
                acc = __builtin_amdgcn_mfma_f32_16x16x32_bf16(af[rt][s], bA[s], acc, 0, 0, 0);
            if (l15 < 4) {
                #pragma unroll
                for (int r = 0; r < 4; ++r) {
                    int k = k0 + rt * 16 + quad * 4 + r;
                    btT[(size_t)l15 * NT + (size_t)k * 256 + j0] = acc[r];   // transposed
                }
            }
        }
    }
#undef LOADB
#undef EVEN
#undef ODD
}

// ---------------------------------------------------------------- kernel 2
// Attention per (i,h).  4 j-tiles of 64 rows; wave owns 16 rows.
// R9-EXACT structure (best measured: attn 52.7us): two k-halves with
// sacc[8] (32 live regs), full pl (disjoint per-wave rows, no WAR reuse),
// one barrier total, launch_bounds(256,3), no-max softmax with deferred
// normalization, gate dwords prefetched at jt-top, manual f2bf conversions
// (compiler-scheduled; NO inline asm on the critical path), exp2-domain
// softmax via __builtin_amdgcn_exp2f (logits pre-scaled by log2e).
__global__ __launch_bounds__(256, 3)
void attn(const short* __restrict__ qt, const short* __restrict__ kt,
          const short* __restrict__ vt, const short* __restrict__ gt,
          const float* __restrict__ btT, short* __restrict__ og) {
    __shared__ short vT[32 * VTP];    // [c_perm][key]   17152 B
    __shared__ short pl[64 * VTP];    // [j_local][key]  34304 B
    const int tid = threadIdx.x;
    const int h = blockIdx.x >> 8, i = blockIdx.x & 255;
    const int wv = tid >> 6, lane = tid & 63;
    const int quad = lane >> 4, l15 = lane & 15;

    const short* kbase = kt + ((size_t)h * NT + (size_t)i * 256) * CHD;
    const short* vbase = vt + ((size_t)h * NT + (size_t)i * 256) * CHD;
    const short* qbase = qt + ((size_t)h * NT + (size_t)i * 256) * CHD;
    const short* gbase = gt + ((size_t)h * NT + (size_t)i * 256) * CHD;
    const float* btTb = btT + (size_t)h * NT;

    // stage v transposed with even/odd permute: col c -> row (c odd ? 16+c/2 : c/2)
    for (int g = tid; g < 1024; g += 256) {
        int key = g >> 2, p = g & 3;
        short8 s = *(const short8*)(vbase + key * CHD + p * 8);
        #pragma unroll
        for (int cc = 0; cc < 8; ++cc) {
            int c = p * 8 + cc;
            int row = (c & 1) ? 16 + (c >> 1) : (c >> 1);
            vT[row * VTP + key] = s[cc];
        }
    }
    __syncthreads();   // the only barrier: vT ready, read-only afterwards

    for (int jt = 0; jt < 4; ++jt) {
        int jbase = jt * 64 + wv * 16;
        short8 aq = *(const short8*)(qbase + (jbase + l15) * CHD + quad * 8);
        // prefetch gate dwords for this jt (consumed at the store)
        unsigned gw0 = *(const unsigned*)(gbase + (size_t)(jbase + quad * 4) * CHD + 2 * l15);
        unsigned gw1 = *(const unsigned*)(gbase + (size_t)(jbase + quad * 4 + 1) * CHD + 2 * l15);
        unsigned gw2 = *(const unsigned*)(gbase + (size_t)(jbase + quad * 4 + 2) * CHD + 2 * l15);
        unsigned gw3 = *(const unsigned*)(gbase + (size_t)(jbase + quad * 4 + 3) * CHD + 2 * l15);

        float sm[4] = {0.f, 0.f, 0.f, 0.f};
        // two k-halves: sacc[8] live at a time (32 regs)
        #pragma unroll
        for (int kh = 0; kh < 2; ++kh) {
            f32x4 sacc[8];
            __builtin_amdgcn_s_setprio(1);
            #pragma unroll
            for (int t = 0; t < 8; ++t) {
                int tt = kh * 8 + t;
                f32x4 c = *(const f32x4*)(btTb + (size_t)(tt * 16 + l15) * 256 + jbase + quad * 4);
                short8 bk = *(const short8*)(kbase + (tt * 16 + l15) * CHD + quad * 8);
                sacc[t] = __builtin_amdgcn_mfma_f32_16x16x32_bf16(aq, bk, c, 0, 0, 0);
            }
            __builtin_amdgcn_s_setprio(0);
            #pragma unroll
            for (int t = 0; t < 8; ++t)
                #pragma unroll
                for (int r = 0; r < 4; ++r) {
                    float e = __builtin_amdgcn_exp2f(sacc[t][r]);   // logits pre-scaled by log2e
                    sacc[t][r] = e;
                    sm[r] += e;
                }
            // P-half -> LDS (own wave's rows; overlaps next half's QK issue)
            #pragma unroll
            for (int t = 0; t < 8; ++t)
                #pragma unroll
                for (int r = 0; r < 4; ++r)
                    pl[(wv * 16 + quad * 4 + r) * VTP + (kh * 8 + t) * 16 + l15] = f2bf(sacc[t][r]);
        }
        #pragma unroll
        for (int m = 1; m < 16; m <<= 1)
            #pragma unroll
            for (int r = 0; r < 4; ++r) sm[r] += __shfl_xor(sm[r], m, 16);
        float inv[4];
        #pragma unroll
        for (int r = 0; r < 4; ++r) inv[r] = 1.f / sm[r];

        // PV (no barrier: same-wave DS ordering covers our writes)
        f32x4 oacc[2];
        oacc[0] = f32x4{0.f, 0.f, 0.f, 0.f};
        oacc[1] = f32x4{0.f, 0.f, 0.f, 0.f};
        __builtin_amdgcn_s_setprio(1);
        #pragma unroll
        for (int ks = 0; ks < 8; ++ks) {
            short8 ap = *(const short8*)&pl[(wv * 16 + l15) * VTP + ks * 32 + quad * 8];
            #pragma unroll
            for (int nt = 0; nt < 2; ++nt) {
                short8 bv = *(const short8*)&vT[(nt * 16 + l15) * VTP + ks * 32 + quad * 8];
                oacc[nt] = __builtin_amdgcn_mfma_f32_16x16x32_bf16(ap, bv, oacc[nt], 0, 0, 0);
            }
        }
        __builtin_amdgcn_s_setprio(0);
        // gate + deferred 1/sum + store: column pair 2*l15(+1) of row j -> dword
        unsigned gws[4] = {gw0, gw1, gw2, gw3};
        #pragma unroll
        for (int r = 0; r < 4; ++r) {
            int j = jbase + quad * 4 + r;
            float g0 = bf2f((short)(gws[r] & 0xffff)) * inv[r];
            float g1 = bf2f((short)(gws[r] >> 16)) * inv[r];
            unsigned pk = ((unsigned)(unsigned short)f2bf(oacc[0][r] * g0))
                        | (((unsigned)(unsigned short)f2bf(oacc[1][r] * g1)) << 16);
            *(unsigned*)&og[((size_t)i * 256 + j) * CP + h * CHD + 2 * l15] = pk;
        }
    }
}

// ---------------------------------------------------------------- kernel 3
// out = og[65536,128] @ Wout[128,128]  (bf16 MFMA, fp32 out)
// R16: af fragments STREAMED per row-tile from LDS instead of all 16 held
// (was ~64 persistent VGPR on top of bE/bO's 64 -> ~165 total -> 2 waves/
// SIMD, round-0-ln_proj-style latency serialization).  Persistent state now
// bE/bO(64) + af(16) + acc(8) + addr => ~110 VGPR -> 4 waves/SIMD.
// B still loaded ONCE per wave (proven R4 structure); LDS b128 af re-reads
// cost ~12cy each.
__global__ __launch_bounds__(256)
void out_gemm(const short* __restrict__ og, const short* __restrict__ woutT,
              float* __restrict__ out) {
    __shared__ short al[64 * 136];
    const int tid = threadIdx.x;
    const int wv = tid >> 6, lane = tid & 63;
    const int quad = lane >> 4, l15 = lane & 15;
    const int r0 = blockIdx.x * 64;

    for (int g = tid; g < 1024; g += 256) {
        int row = g >> 4, p = g & 15;
        *(short8*)&al[row * 136 + p * 8] = *(const short8*)(og + (size_t)(r0 + row) * CP + p * 8);
    }

    short8 bE[4], bO[4];
    #pragma unroll
    for (int s = 0; s < 4; ++s) {
        bE[s] = *(const short8*)&woutT[(size_t)(wv * 32 + l15) * 128 + s * 32 + quad * 8];
        bO[s] = *(const short8*)&woutT[(size_t)(wv * 32 + 16 + l15) * 128 + s * 32 + quad * 8];
    }
    __syncthreads();

    #pragma unroll
    for (int rt = 0; rt < 4; ++rt) {
        short8 af[4];
        #pragma unroll
        for (int s = 0; s < 4; ++s)
            af[s] = *(const short8*)&al[(rt * 16 + l15) * 136 + s * 32 + quad * 8];
        f32x4 accE = {0.f, 0.f, 0.f, 0.f}, accO = {0.f, 0.f, 0.f, 0.f};
        #pragma unroll
        for (int s = 0; s < 4; ++s) {
            accE = __builtin_amdgcn_mfma_f32_16x16x32_bf16(af[s], bE[s], accE, 0, 0, 0);
            accO = __builtin_amdgcn_mfma_f32_16x16x32_bf16(af[s], bO[s], accO, 0, 0, 0);
        }
        #pragma unroll
        for (int r = 0; r < 4; ++r) {
            f32x2 pk = {accE[r], accO[r]};
            *(f32x2*)&out[(size_t)(r0 + rt * 16 + quad * 4 + r) * CP + wv * 32 + 2 * l15] = pk;
        }
    }
}

// ---------------------------------------------------------------- launch
extern "C" void kernel_launch(void* const* d_in, const int* in_sizes, int n_in,
                              void* d_out, int out_size, void* d_ws, size_t ws_size,
                              hipStream_t stream) {
    (void)in_sizes; (void)n_in; (void)out_size; (void)ws_size;
    const float* pair  = (const float*)d_in[0];
    const float* gamma = (const float*)d_in[1];
    const float* beta  = (const float*)d_in[2];
    const float* Wq    = (const float*)d_in[3];
    const float* Wk    = (const float*)d_in[4];
    const float* Wv    = (const float*)d_in[5];
    const float* Wb    = (const float*)d_in[6];
    const float* Wg    = (const float*)d_in[7];
    const float* Wout  = (const float*)d_in[8];
    float* out = (float*)d_out;

    char* ws = (char*)d_ws;
    const size_t SZ_QKVG = (size_t)NH * NT * CHD * 2;           // 16 MB each
    short* wcat  = (short*)(ws);                                 // 528*128*2 = 135168
    short* woutT = (short*)(ws + 135168);                        // 32768
    short* qt    = (short*)(ws + 167936);
    short* kt    = (short*)(ws + 167936 + SZ_QKVG);
    short* vt    = (short*)(ws + 167936 + 2 * SZ_QKVG);
    short* gt    = (short*)(ws + 167936 + 3 * SZ_QKVG);
    float* btT   = (float*)(ws + 167936 + 4 * SZ_QKVG);          // NH*NT*4 = 1 MB
    short* og    = (short*)(ws + 167936 + 4 * SZ_QKVG + (size_t)NH * NT * 4);

    hipLaunchKernelGGL(pack_weights, dim3(328), dim3(256), 0, stream,
                       Wq, Wk, Wv, Wb, Wg, Wout, wcat, woutT);
    hipLaunchKernelGGL(ln_proj, dim3(1024), dim3(256), 0, stream,
                       pair, gamma, beta, wcat, qt, kt, vt, gt, btT);
    hipLaunchKernelGGL(attn, dim3(1024), dim3(256), 0, stream,
                       qt, kt, vt, gt, btT, og);
    hipLaunchKernelGGL(out_gemm, dim3(1024), dim3(256), 0, stream,
                       og, woutT, out);
}